// Round 5
// baseline (26368.121 us; speedup 1.0000x reference)
//
#include <hip/hip_runtime.h>

#define TT 8192
#define HH 200
#define G4 800
#define KREG 102    // fp32 reg columns: k in [98,200)
#define RD 1024     // pre1 ring depth
#define RDM 1023
#define BPWIN 900

typedef unsigned long long u64;
typedef unsigned int u32;

__device__ __forceinline__ float sigmoidf_(float x){ return 1.0f/(1.0f+__expf(-x)); }
__device__ __forceinline__ float tanhf_(float x){
    float e = __expf(2.0f*fabsf(x));
    float r = 1.0f - 2.0f/(e + 1.0f);
    return copysignf(r, x);
}
__device__ __forceinline__ u64 pck(u32 tag, float v){
    return ((u64)tag << 32) | (u64)__float_as_uint(v);
}
__device__ __forceinline__ u64 ald(const u64* p){
    return __hip_atomic_load((u64*)p, __ATOMIC_RELAXED, __HIP_MEMORY_SCOPE_AGENT);
}
__device__ __forceinline__ void ast(u64* p, u64 v){
    __hip_atomic_store(p, v, __ATOMIC_RELAXED, __HIP_MEMORY_SCOPE_AGENT);
}
__device__ __forceinline__ u32 bf16rne(float f){   // fp32 -> bf16 round-nearest-even
    u32 x = __float_as_uint(f);
    return (x + 0x7fffu + ((x >> 16) & 1u)) >> 16;
}
__device__ __forceinline__ float bflo(u32 u){ return __uint_as_float(u << 16); }
__device__ __forceinline__ float bfhi(u32 u){ return __uint_as_float(u & 0xffff0000u); }

// single tagged value poll
__device__ __forceinline__ float poll1(const u64* p, u32 tag){
    u64 v;
    do { v = ald(p); } while ((u32)(v >> 32) != tag);
    return __uint_as_float((u32)v);
}
// 224 lanes fetch 800 tagged values (4 or 3 each), batched in flight
__device__ __forceinline__ void poll4(const u64* slot, u32 tag, int m, float* o){
    const bool g3 = (m < 128);
    u64 v0, v1, v2, v3 = 0;
    for(;;){
        v0 = ald(slot + m);
        v1 = ald(slot + m + 224);
        v2 = ald(slot + m + 448);
        if (g3) v3 = ald(slot + m + 672);
        if ((u32)(v0>>32)==tag && (u32)(v1>>32)==tag && (u32)(v2>>32)==tag &&
            (!g3 || (u32)(v3>>32)==tag)) break;
    }
    o[0] = __uint_as_float((u32)v0);
    o[1] = __uint_as_float((u32)v1);
    o[2] = __uint_as_float((u32)v2);
    o[3] = g3 ? __uint_as_float((u32)v3) : 0.f;
}

// roles: 0 = layer-0 recurrence (1 CU), 1 = layer-1 recurrence (1 CU),
//        2..5 = pre1 stream (gate q = role-2).
// Recurrence CU: 800 primaries each own a full gate row. K in [98,200) from
// 102 pinned fp32 VGPRs; K in [0,98) from packed-bf16 LDS. Zero cross-CU
// traffic on the per-step critical path.
__global__ __launch_bounds__(1024, 4)
void lstm_pipe(const float* __restrict__ x,
               const float* __restrict__ Wih0, const float* __restrict__ Whh0,
               const float* __restrict__ bih0, const float* __restrict__ bhh0,
               const float* __restrict__ Wih1, const float* __restrict__ Whh1,
               const float* __restrict__ bih1, const float* __restrict__ bhh1,
               const float* __restrict__ Wout, const float* __restrict__ bout,
               u64* __restrict__ h0s,   // [TT][HH] tagged
               u64* __restrict__ p1r,   // [RD][G4] tagged ring
               u32* __restrict__ prog,  // [1] layer-1 progress
               float* __restrict__ out)
{
    const int role = blockIdx.x;
    const int tid  = threadIdx.x;

    __shared__ u32   wl4[12 * G4 * 4];   // 153,600B: k=0..95 packed bf16 pairs
    __shared__ u32   wl1[G4];            //   3,200B: k=96,97 pair
    __shared__ float h_lds[HH];          //     800B
    __shared__ float s_pre[G4];          //   3,200B
    __shared__ float xr[8];              //      32B (L0 x ring)

    // ================= pre1 streaming stage =================
    if (role >= 2) {
        const int q = role - 2;
        float* hb0 = h_lds;              // reuse as h0 double buffer
        float* hb1 = s_pre;
        int grow = 0; float bs = 0.f;
        float w[50];
        if (tid < 800) {
            const int rl = tid >> 2, kq = tid & 3;
            grow = q * 200 + rl;
            const float* wr = Wih1 + (size_t)grow * HH + kq * 50;
            #pragma unroll
            for (int k = 0; k < 50; ++k) w[k] = wr[k];
            #pragma unroll
            for (int k = 0; k < 50; ++k) asm volatile("" : "+v"(w[k]));
            if (kq == 0) { bs = bih1[grow] + bhh1[grow]; asm volatile("" : "+v"(bs)); }
        } else if (tid < 1000) {
            hb0[tid - 800] = poll1(&h0s[tid - 800], 1u);   // preload h0[0]
        }
        u32 prog_c = 0;
        __syncthreads();
        for (int t = 0; t < TT; ++t) {
            const float* hb = (t & 1) ? hb1 : hb0;
            float s = 0.f;
            if (tid < 800) {
                const int kq = tid & 3;
                float a0 = 0.f, a1 = 0.f;
                const float2* h2 = (const float2*)(hb + kq * 50);
                #pragma unroll
                for (int m2 = 0; m2 < 25; ++m2) {
                    float2 hv = h2[m2];
                    a0 += w[2*m2]   * hv.x;
                    a1 += w[2*m2+1] * hv.y;
                }
                s = a0 + a1;
                s += __shfl_xor(s, 1);
                s += __shfl_xor(s, 2);
            } else if (tid < 1000) {
                if (t + 1 < TT) {
                    float* hn = ((t + 1) & 1) ? hb1 : hb0;
                    hn[tid - 800] = poll1(&h0s[(size_t)(t+1)*HH + (tid-800)],
                                          (u32)(t + 2));
                }
            } else if (tid == 1008) {
                while ((int)(t + 1) - (int)prog_c >= BPWIN) {
                    __builtin_amdgcn_s_sleep(8);
                    prog_c = __hip_atomic_load(prog, __ATOMIC_RELAXED,
                                               __HIP_MEMORY_SCOPE_AGENT);
                }
            }
            __syncthreads();
            if (tid < 800 && (tid & 3) == 0)
                ast(&p1r[(size_t)(t & RDM) * G4 + grow], pck((u32)(t+1), s + bs));
        }
        return;
    }

    // ================= recurrence stages (1 CU each) =================
    const bool L0 = (role == 0);
    const float* Whh = L0 ? Whh0 : Whh1;

    // LDS weight tier: k in [0,98) as packed bf16 pairs
    for (int idx = tid; idx < G4 * 49; idx += 1024) {
        const int r = idx / 49, cu = idx % 49;
        const int k = cu * 2;
        const u32 p = (bf16rne(Whh[(size_t)r * HH + k + 1]) << 16)
                    |  bf16rne(Whh[(size_t)r * HH + k]);
        if (cu < 48) wl4[(((cu >> 2) * G4) + r) * 4 + (cu & 3)] = p;
        else         wl1[r] = p;
    }
    // reg weight tier: k in [98,200)
    float w[KREG];
    float wih = 0.f, bs = 0.f;
    if (tid < G4) {
        const float* wr = Whh + (size_t)tid * HH + 98;
        #pragma unroll
        for (int k = 0; k < KREG; ++k) w[k] = wr[k];
        #pragma unroll
        for (int k = 0; k < KREG; ++k) asm volatile("" : "+v"(w[k]));
        if (L0) {
            bs  = bih0[tid] + bhh0[tid];
            wih = Wih0[tid];
            asm volatile("" : "+v"(bs));
            asm volatile("" : "+v"(wih));
        }
    }
    if (tid < HH) h_lds[tid] = 0.f;

    float c = 0.f;          // gate lanes (800..999)
    float o0=0.f, o1=0.f, o2=0.f, o3=0.f;   // L1 pre prefetch regs
    if (!L0 && tid >= 800) {                // preload pre1[0] -> s_pre
        float o[4];
        poll4(p1r, 1u, tid - 800, o);
        const int m = tid - 800;
        s_pre[m]       = o[0];
        s_pre[m + 224] = o[1];
        s_pre[m + 448] = o[2];
        if (m < 128) s_pre[m + 672] = o[3];
    }
    if (L0 && tid == 1000) xr[0] = x[0];
    __syncthreads();

    for (int t = 0; t < TT; ++t) {
        // ---- phase 2: 800 primaries FMA; lanes 800+ prefetch next input ----
        if (tid < G4) {
            const int r = tid;
            float a0=0.f, a1=0.f, a2=0.f, a3=0.f;
            const float4* h4 = (const float4*)h_lds;
            #pragma unroll
            for (int g = 0; g < 12; ++g) {               // k = g*8 .. g*8+7
                uint4 u = *(const uint4*)&wl4[((g * G4) + r) * 4];
                float4 hA = h4[g*2];
                float4 hB = h4[g*2 + 1];
                a0 += bflo(u.x) * hA.x;  a1 += bfhi(u.x) * hA.y;
                a2 += bflo(u.y) * hA.z;  a3 += bfhi(u.y) * hA.w;
                a0 += bflo(u.z) * hB.x;  a1 += bfhi(u.z) * hB.y;
                a2 += bflo(u.w) * hB.z;  a3 += bfhi(u.w) * hB.w;
            }
            {   // k = 96,97 from wl1; k = 98,99 from regs
                const u32 u = wl1[r];
                const float2 hv = *(const float2*)(h_lds + 96);
                a0 += bflo(u) * hv.x;
                a1 += bfhi(u) * hv.y;
                a2 += w[0] * h_lds[98];
                a3 += w[1] * h_lds[99];
            }
            #pragma unroll
            for (int k4 = 0; k4 < 25; ++k4) {            // k = 100 + 4*k4
                float4 hv = h4[25 + k4];
                a0 += w[2 + 4*k4    ] * hv.x;
                a1 += w[2 + 4*k4 + 1] * hv.y;
                a2 += w[2 + 4*k4 + 2] * hv.z;
                a3 += w[2 + 4*k4 + 3] * hv.w;
            }
            const float acc = (a0 + a1) + (a2 + a3);
            if (L0) s_pre[r] = acc + xr[t & 7] * wih + bs;
            else    s_pre[r] = acc + s_pre[r];
        } else {
            if (!L0) {
                if (t + 1 < TT) {
                    float o[4];
                    poll4(&p1r[(size_t)((t + 1) & RDM) * G4], (u32)(t + 2),
                          tid - 800, o);
                    o0 = o[0]; o1 = o[1]; o2 = o[2]; o3 = o[3];
                }
            } else if (tid == 1000 && t + 1 < TT) {
                o0 = x[t + 1];
            }
        }
        __syncthreads();
        // ---- phase 3: gates on lanes 800..999 ----
        if (tid >= 800 && tid < 1000) {
            const int n = tid - 800;
            const float ig = sigmoidf_(s_pre[n]);
            const float fg = sigmoidf_(s_pre[200 + n]);
            const float gg = tanhf_  (s_pre[400 + n]);
            const float og = sigmoidf_(s_pre[600 + n]);
            c = fg * c + ig * gg;
            const float h = og * tanhf_(c);
            h_lds[n] = h;
            if (L0) ast(&h0s[(size_t)t * HH + n], pck((u32)(t + 1), h));
        } else if (!L0 && tid == 1012 && (t & 63) == 63) {
            __hip_atomic_store(prog, (u32)(t + 1), __ATOMIC_RELAXED,
                               __HIP_MEMORY_SCOPE_AGENT);
        }
        __syncthreads();
        // ---- phase 4: stage next step's inputs ----
        if (!L0 && tid >= 800 && t + 1 < TT) {
            const int m = tid - 800;
            s_pre[m]       = o0;
            s_pre[m + 224] = o1;
            s_pre[m + 448] = o2;
            if (m < 128) s_pre[m + 672] = o3;
        }
        if (L0 && tid == 1000 && t + 1 < TT) xr[(t + 1) & 7] = o0;
        __syncthreads();
    }

    // ---- linear head on final h1 (L1 block) ----
    if (!L0 && tid < 64) {
        float s2 = 0.f;
        for (int k = tid; k < HH; k += 64) s2 += h_lds[k] * Wout[k];
        #pragma unroll
        for (int off = 32; off > 0; off >>= 1) s2 += __shfl_down(s2, off);
        if (tid == 0) out[0] = s2 + bout[0];
    }
}

extern "C" void kernel_launch(void* const* d_in, const int* in_sizes, int n_in,
                              void* d_out, int out_size, void* d_ws, size_t ws_size,
                              hipStream_t stream) {
    const float* x    = (const float*)d_in[0];
    const float* Wih0 = (const float*)d_in[1];
    const float* Whh0 = (const float*)d_in[2];
    const float* bih0 = (const float*)d_in[3];
    const float* bhh0 = (const float*)d_in[4];
    const float* Wih1 = (const float*)d_in[5];
    const float* Whh1 = (const float*)d_in[6];
    const float* bih1 = (const float*)d_in[7];
    const float* bhh1 = (const float*)d_in[8];
    const float* Wout = (const float*)d_in[9];
    const float* bout = (const float*)d_in[10];
    float* out = (float*)d_out;

    char* ws = (char*)d_ws;
    // h0s 13,107,200 | p1r 6,553,600 | prog 64
    u64* h0s  = (u64*)ws;
    u64* p1r  = (u64*)(ws + 13107200);
    u32* prog = (u32*)(ws + 19660800);

    // clear all tags/progress every launch (graph-safe, deterministic)
    hipMemsetAsync(ws, 0, 19660864, stream);

    hipLaunchKernelGGL(lstm_pipe, dim3(6), dim3(1024), 0, stream,
        x, Wih0, Whh0, bih0, bhh0, Wih1, Whh1, bih1, bhh1, Wout, bout,
        h0s, p1r, prog, out);
}

// Round 6
// 16023.976 us; speedup vs baseline: 1.6455x; 1.6455x over previous
//
#include <hip/hip_runtime.h>

#define TT 8192
#define HH 200
#define G4 800
#define NLJ 9       // LDS-tier uint4 groups/row (36 pairs = cols 0..71)
#define NWR 64      // reg-tier pairs/row (cols 72..199)
#define RD 1024     // pre1 ring depth (steps)
#define RDM 1023
#define BPWIN 900

typedef unsigned long long u64;
typedef unsigned int u32;
typedef _Float16 f16;
typedef _Float16 f16x2 __attribute__((ext_vector_type(2)));

__device__ __forceinline__ float sigmoidf_(float x){ return 1.0f/(1.0f+__expf(-x)); }
__device__ __forceinline__ float tanhf_(float x){
    float e = __expf(2.0f*fabsf(x));
    float r = 1.0f - 2.0f/(e + 1.0f);
    return copysignf(r, x);
}
__device__ __forceinline__ u64 pcku(u32 tag, u32 v){ return ((u64)tag<<32) | v; }
__device__ __forceinline__ u64 pckf(u32 tag, float v){ return pcku(tag, __float_as_uint(v)); }
__device__ __forceinline__ u64 ald(const u64* p){
    return __hip_atomic_load((u64*)p, __ATOMIC_RELAXED, __HIP_MEMORY_SCOPE_AGENT);
}
__device__ __forceinline__ void ast(u64* p, u64 v){
    __hip_atomic_store(p, v, __ATOMIC_RELAXED, __HIP_MEMORY_SCOPE_AGENT);
}
__device__ __forceinline__ u32 pkh(float a, float b){   // fp32x2 -> packed f16 (RNE)
    f16x2 v = { (f16)a, (f16)b };
    return __builtin_bit_cast(u32, v);
}
__device__ __forceinline__ float dot2(u32 a, u32 b, float c){
#if __has_builtin(__builtin_amdgcn_fdot2)
    return __builtin_amdgcn_fdot2(__builtin_bit_cast(f16x2, a),
                                  __builtin_bit_cast(f16x2, b), c, false);
#else
    f16x2 av = __builtin_bit_cast(f16x2, a), bv = __builtin_bit_cast(f16x2, b);
    return c + (float)av[0]*(float)bv[0] + (float)av[1]*(float)bv[1];
#endif
}
__device__ __forceinline__ u32 poll1u(const u64* p, u32 tag){
    u64 v; do { v = ald(p); } while ((u32)(v >> 32) != tag);
    return (u32)v;
}
// 192 lanes (m = tid-832) fetch 800 tagged fp32 values, loads batched in flight
__device__ __forceinline__ void poll5(const u64* slot, u32 tag, int m, float* o){
    const bool g4 = (m < 32);
    u64 v0, v1, v2, v3, v4 = 0;
    for(;;){
        v0 = ald(slot + m);       v1 = ald(slot + m + 192);
        v2 = ald(slot + m + 384); v3 = ald(slot + m + 576);
        if (g4) v4 = ald(slot + m + 768);
        if ((u32)(v0>>32)==tag && (u32)(v1>>32)==tag && (u32)(v2>>32)==tag &&
            (u32)(v3>>32)==tag && (!g4 || (u32)(v4>>32)==tag)) break;
    }
    o[0]=__uint_as_float((u32)v0); o[1]=__uint_as_float((u32)v1);
    o[2]=__uint_as_float((u32)v2); o[3]=__uint_as_float((u32)v3);
    o[4]= g4 ? __uint_as_float((u32)v4) : 0.f;
}

// roles: 0 = layer-0 recurrence, 1 = layer-1 recurrence, 2..5 = pre1 (gate q).
// Recurrence CU: 800 primaries (waves 0-12) each own one gate row, 100 f16-pair
// dot2/step (64 pairs VGPR, 36 pairs LDS). Service waves 13-15: polls + gates +
// restage. Wave-aligned roles: no wave mixes FMA with spin loops.
__global__ __launch_bounds__(1024, 4)
void lstm_pipe(const float* __restrict__ x,
               const float* __restrict__ Wih0, const float* __restrict__ Whh0,
               const float* __restrict__ bih0, const float* __restrict__ bhh0,
               const float* __restrict__ Wih1, const float* __restrict__ Whh1,
               const float* __restrict__ bih1, const float* __restrict__ bhh1,
               const float* __restrict__ Wout, const float* __restrict__ bout,
               u64* __restrict__ hp0,   // [TT][100] tagged packed-f16 h0 pairs
               u64* __restrict__ p1r,   // [RD][G4] tagged fp32 ring
               u32* __restrict__ prog,  // [1] layer-1 progress
               float* __restrict__ out)
{
    const int role = blockIdx.x;
    const int tid  = threadIdx.x;

    __shared__ __align__(16) u32 wl[NLJ * G4 * 4];  // 115,200B
    __shared__ __align__(16) u32 hp_lds[100];       // packed h pairs
    __shared__ float h32[HH];
    __shared__ float s_pre[G4];
    __shared__ float xr[8];
    __shared__ u32 hpbuf[2][100];                   // pre1-stage h0 dbuf

    // ================= pre1 streaming stage =================
    if (role >= 2) {
        const int q = role - 2;
        const int rl = tid >> 2, kq = tid & 3;
        u32 wp[25]; float bs = 0.f; int grow = 0;
        if (tid < 800) {
            grow = q * 200 + rl;
            const float* wr = Wih1 + (size_t)grow * HH + kq * 50;
            #pragma unroll
            for (int i = 0; i < 25; ++i) wp[i] = pkh(wr[2*i], wr[2*i+1]);
            #pragma unroll
            for (int i = 0; i < 25; ++i) asm volatile("" : "+v"(wp[i]));
            if (kq == 0) bs = bih1[grow] + bhh1[grow];
        } else if (tid >= 832 && tid < 932) {
            hpbuf[0][tid - 832] = poll1u(&hp0[tid - 832], 1u);  // preload h0[0]
        }
        u32 prog_c = 0;
        __syncthreads();
        for (int t = 0; t < TT; ++t) {
            if (tid < 800) {
                const u32* hb = hpbuf[t & 1] + kq * 25;
                float a0 = 0.f, a1 = 0.f;
                #pragma unroll
                for (int i = 0; i < 25; i += 2) a0 = dot2(wp[i], hb[i], a0);
                #pragma unroll
                for (int i = 1; i < 25; i += 2) a1 = dot2(wp[i], hb[i], a1);
                float s = a0 + a1;
                s += __shfl_xor(s, 1);
                s += __shfl_xor(s, 2);
                if (kq == 0)
                    ast(&p1r[(size_t)(t & RDM) * G4 + grow],
                        pckf((u32)(t + 1), s + bs));
            } else if (tid >= 832 && tid < 932) {
                if (t + 1 < TT)
                    hpbuf[(t + 1) & 1][tid - 832] =
                        poll1u(&hp0[(size_t)(t + 1) * 100 + (tid - 832)],
                               (u32)(t + 2));
            } else if (tid == 1008) {
                while ((int)(t + 1) - (int)prog_c >= BPWIN) {
                    __builtin_amdgcn_s_sleep(8);
                    prog_c = __hip_atomic_load(prog, __ATOMIC_RELAXED,
                                               __HIP_MEMORY_SCOPE_AGENT);
                }
            }
            __syncthreads();
        }
        return;
    }

    // ================= recurrence stages (1 CU each) =================
    const bool L0 = (role == 0);
    const float* Whh = L0 ? Whh0 : Whh1;

    // LDS weight tier: pairs p in [0,36) -> cols [0,72)
    for (int idx = tid; idx < G4 * 36; idx += 1024) {
        const int r = idx / 36, p = idx % 36;
        const float* wr = Whh + (size_t)r * HH;
        wl[(((p >> 2) * G4 + r) << 2) + (p & 3)] = pkh(wr[2*p], wr[2*p + 1]);
    }
    // reg weight tier: pairs 36+i -> cols [72,200)
    u32 w[NWR]; float wih = 0.f, bs = 0.f;
    if (tid < G4) {
        const float* wr = Whh + (size_t)tid * HH + 72;
        #pragma unroll
        for (int i = 0; i < NWR; ++i) w[i] = pkh(wr[2*i], wr[2*i + 1]);
        #pragma unroll
        for (int i = 0; i < NWR; ++i) asm volatile("" : "+v"(w[i]));
        if (L0) {
            bs = bih0[tid] + bhh0[tid];
            wih = Wih0[tid];
            asm volatile("" : "+v"(bs));
            asm volatile("" : "+v"(wih));
        }
    }
    if (tid < 100) hp_lds[tid] = 0u;
    if (tid < HH) h32[tid] = 0.f;

    float c = 0.f, c2 = 0.f;
    float o0=0.f, o1=0.f, o2=0.f, o3=0.f, o4=0.f;
    if (!L0 && tid >= 832) {        // preload pre1[0] straight into s_pre
        float o[5];
        poll5(p1r, 1u, tid - 832, o);
        const int m = tid - 832;
        s_pre[m] = o[0]; s_pre[m+192] = o[1]; s_pre[m+384] = o[2];
        s_pre[m+576] = o[3];
        if (m < 32) s_pre[m+768] = o[4];
    }
    if (L0 && tid == 832) xr[0] = x[0];
    __syncthreads();

    for (int t = 0; t < TT; ++t) {
        // ---- phase A: primaries FMA; service waves poll next input ----
        if (tid < G4) {
            const uint4* hp4 = (const uint4*)hp_lds;
            float a0=0.f, a1=0.f, a2=0.f, a3=0.f;
            #pragma unroll
            for (int j = 0; j < NLJ; ++j) {
                const uint4 hu = hp4[j];
                const uint4 wu = *(const uint4*)&wl[(j * G4 + tid) << 2];
                a0 = dot2(wu.x, hu.x, a0);
                a1 = dot2(wu.y, hu.y, a1);
                a2 = dot2(wu.z, hu.z, a2);
                a3 = dot2(wu.w, hu.w, a3);
                if ((j % 3) == 2) __builtin_amdgcn_sched_barrier(0);
            }
            #pragma unroll
            for (int j = NLJ; j < 25; ++j) {
                const uint4 hu = hp4[j];
                const int i = (j - NLJ) * 4;
                a0 = dot2(w[i],     hu.x, a0);
                a1 = dot2(w[i + 1], hu.y, a1);
                a2 = dot2(w[i + 2], hu.z, a2);
                a3 = dot2(w[i + 3], hu.w, a3);
                if ((j % 4) == 3) __builtin_amdgcn_sched_barrier(0);
            }
            const float acc = (a0 + a1) + (a2 + a3);
            if (L0) s_pre[tid] = acc + xr[t & 7] * wih + bs;
            else    s_pre[tid] = acc + s_pre[tid];
        } else if (tid >= 832) {
            if (!L0) {
                if (t + 1 < TT) {
                    float o[5];
                    poll5(&p1r[(size_t)((t + 1) & RDM) * G4], (u32)(t + 2),
                          tid - 832, o);
                    o0=o[0]; o1=o[1]; o2=o[2]; o3=o[3]; o4=o[4];
                }
            } else if (tid == 832 && t + 1 < TT) {
                o0 = x[t + 1];
            }
        }
        __syncthreads();
        // ---- phase B: gates on service waves (192 lanes, 8 take 2 neurons) ----
        if (tid >= 832) {
            const int n = tid - 832;
            const float ig = sigmoidf_(s_pre[n]);
            const float fg = sigmoidf_(s_pre[200 + n]);
            const float gg = tanhf_  (s_pre[400 + n]);
            const float og = sigmoidf_(s_pre[600 + n]);
            c = fg * c + ig * gg;
            const float h = og * tanhf_(c);
            h32[n] = h;
            const float hpart = __shfl_xor(h, 1);
            u32 pk2 = 0;
            if (!(n & 1)) { pk2 = pkh(h, hpart); hp_lds[n >> 1] = pk2; }
            float h2 = 0.f;
            if (n < 8) {
                const int n2 = 192 + n;
                const float ig2 = sigmoidf_(s_pre[n2]);
                const float fg2 = sigmoidf_(s_pre[200 + n2]);
                const float gg2 = tanhf_  (s_pre[400 + n2]);
                const float og2 = sigmoidf_(s_pre[600 + n2]);
                c2 = fg2 * c2 + ig2 * gg2;
                h2 = og2 * tanhf_(c2);
                h32[n2] = h2;
            }
            const float h2part = __shfl_xor(h2, 1);
            u32 pk2b = 0;
            if (n < 8 && !(n & 1)) { pk2b = pkh(h2, h2part); hp_lds[96 + (n>>1)] = pk2b; }
            if (L0 && !(n & 1)) {
                ast(&hp0[(size_t)t * 100 + (n >> 1)], pcku((u32)(t + 1), pk2));
                if (n < 8)
                    ast(&hp0[(size_t)t * 100 + 96 + (n >> 1)],
                        pcku((u32)(t + 1), pk2b));
            }
        } else if (!L0 && tid == 800 && (t & 63) == 63) {
            __hip_atomic_store(prog, (u32)(t + 1), __ATOMIC_RELAXED,
                               __HIP_MEMORY_SCOPE_AGENT);
        }
        __syncthreads();
        // ---- phase C: restage next step's inputs ----
        if (tid >= 832 && t + 1 < TT) {
            if (!L0) {
                const int m = tid - 832;
                s_pre[m] = o0; s_pre[m+192] = o1; s_pre[m+384] = o2;
                s_pre[m+576] = o3;
                if (m < 32) s_pre[m+768] = o4;
            } else if (tid == 832) {
                xr[(t + 1) & 7] = o0;
            }
        }
        __syncthreads();
    }

    // ---- linear head on final h1 (L1 block) ----
    if (!L0 && tid < 64) {
        float s2 = 0.f;
        for (int k = tid; k < HH; k += 64) s2 += h32[k] * Wout[k];
        #pragma unroll
        for (int off = 32; off > 0; off >>= 1) s2 += __shfl_down(s2, off);
        if (tid == 0) out[0] = s2 + bout[0];
    }
}

extern "C" void kernel_launch(void* const* d_in, const int* in_sizes, int n_in,
                              void* d_out, int out_size, void* d_ws, size_t ws_size,
                              hipStream_t stream) {
    const float* x    = (const float*)d_in[0];
    const float* Wih0 = (const float*)d_in[1];
    const float* Whh0 = (const float*)d_in[2];
    const float* bih0 = (const float*)d_in[3];
    const float* bhh0 = (const float*)d_in[4];
    const float* Wih1 = (const float*)d_in[5];
    const float* Whh1 = (const float*)d_in[6];
    const float* bih1 = (const float*)d_in[7];
    const float* bhh1 = (const float*)d_in[8];
    const float* Wout = (const float*)d_in[9];
    const float* bout = (const float*)d_in[10];
    float* out = (float*)d_out;

    char* ws = (char*)d_ws;
    // hp0 6,553,600 | p1r 6,553,600 | prog 64
    u64* hp0  = (u64*)ws;
    u64* p1r  = (u64*)(ws + 6553600);
    u32* prog = (u32*)(ws + 13107200);

    // clear all tags/progress every launch (graph-safe, deterministic)
    hipMemsetAsync(ws, 0, 13107264, stream);

    hipLaunchKernelGGL(lstm_pipe, dim3(6), dim3(1024), 0, stream,
        x, Wih0, Whh0, bih0, bhh0, Wih1, Whh1, bih1, bhh1, Wout, bout,
        hp0, p1r, prog, out);
}

// Round 7
// 15151.588 us; speedup vs baseline: 1.7403x; 1.0576x over previous
//
#include <hip/hip_runtime.h>

#define TT 8192
#define HH 200
#define G4 800
#define NLJ 9       // LDS-tier uint4 groups/row (36 pairs = cols 0..71)
#define NWR 64      // reg-tier pairs/row (cols 72..199)
#define RD 1024     // pre1 ring depth (steps)
#define RDM 1023
#define BPWIN 900

typedef unsigned long long u64;
typedef unsigned int u32;
typedef _Float16 f16;
typedef _Float16 f16x2 __attribute__((ext_vector_type(2)));

__device__ __forceinline__ float sigmoidf_(float x){ return 1.0f/(1.0f+__expf(-x)); }
__device__ __forceinline__ float tanhf_(float x){
    float e = __expf(2.0f*fabsf(x));
    float r = 1.0f - 2.0f/(e + 1.0f);
    return copysignf(r, x);
}
__device__ __forceinline__ u64 pcku(u32 tag, u32 v){ return ((u64)tag<<32) | v; }
__device__ __forceinline__ u64 pckf(u32 tag, float v){ return pcku(tag, __float_as_uint(v)); }
__device__ __forceinline__ u64 ald(const u64* p){
    return __hip_atomic_load((u64*)p, __ATOMIC_RELAXED, __HIP_MEMORY_SCOPE_AGENT);
}
__device__ __forceinline__ void ast(u64* p, u64 v){
    __hip_atomic_store(p, v, __ATOMIC_RELAXED, __HIP_MEMORY_SCOPE_AGENT);
}
__device__ __forceinline__ u32 pkh(float a, float b){   // fp32x2 -> packed f16 (RNE)
    f16x2 v = { (f16)a, (f16)b };
    return __builtin_bit_cast(u32, v);
}
__device__ __forceinline__ float dot2(u32 a, u32 b, float c){
#if __has_builtin(__builtin_amdgcn_fdot2)
    return __builtin_amdgcn_fdot2(__builtin_bit_cast(f16x2, a),
                                  __builtin_bit_cast(f16x2, b), c, false);
#else
    f16x2 av = __builtin_bit_cast(f16x2, a), bv = __builtin_bit_cast(f16x2, b);
    return c + (float)av[0]*(float)bv[0] + (float)av[1]*(float)bv[1];
#endif
}
__device__ __forceinline__ u32 poll1u(const u64* p, u32 tag){
    u64 v; do { v = ald(p); } while ((u32)(v >> 32) != tag);
    return (u32)v;
}
// 192 lanes (m = tid-832) fetch 800 tagged fp32 values, loads batched in flight
__device__ __forceinline__ void poll5(const u64* slot, u32 tag, int m, float* o){
    const bool g4 = (m < 32);
    u64 v0, v1, v2, v3, v4 = 0;
    for(;;){
        v0 = ald(slot + m);       v1 = ald(slot + m + 192);
        v2 = ald(slot + m + 384); v3 = ald(slot + m + 576);
        if (g4) v4 = ald(slot + m + 768);
        if ((u32)(v0>>32)==tag && (u32)(v1>>32)==tag && (u32)(v2>>32)==tag &&
            (u32)(v3>>32)==tag && (!g4 || (u32)(v4>>32)==tag)) break;
    }
    o[0]=__uint_as_float((u32)v0); o[1]=__uint_as_float((u32)v1);
    o[2]=__uint_as_float((u32)v2); o[3]=__uint_as_float((u32)v3);
    o[4]= g4 ? __uint_as_float((u32)v4) : 0.f;
}

// roles: 0 = layer-0 recurrence, 1 = layer-1 recurrence, 2..5 = pre1 (gate q).
// Recurrence CU: 800 primaries (waves 0-12) each own one gate row, 100 f16-pair
// dot2/step (64 pairs VGPR, 36 pairs LDS). Service waves 13-15: polls + gates +
// restage. 2 barriers/step via s_in/hp_lds/xr double-buffers.
// launch_bounds(1024,1): min-waves=1 so the allocator allocates need (~95)
// instead of cap/2=64 (rounds 5/6 failure mode).
__global__ __launch_bounds__(1024, 1)
void lstm_pipe(const float* __restrict__ x,
               const float* __restrict__ Wih0, const float* __restrict__ Whh0,
               const float* __restrict__ bih0, const float* __restrict__ bhh0,
               const float* __restrict__ Wih1, const float* __restrict__ Whh1,
               const float* __restrict__ bih1, const float* __restrict__ bhh1,
               const float* __restrict__ Wout, const float* __restrict__ bout,
               u64* __restrict__ hp0,   // [TT][100] tagged packed-f16 h0 pairs
               u64* __restrict__ p1r,   // [RD][G4] tagged fp32 ring
               u32* __restrict__ prog,  // [1] layer-1 progress
               float* __restrict__ out)
{
    const int role = blockIdx.x;
    const int tid  = threadIdx.x;

    __shared__ __align__(16) u32 wl[NLJ * G4 * 4];  // 115,200B
    __shared__ __align__(16) u32 hp_lds[2][100];    // packed h pairs (dbuf)
    __shared__ float h32[HH];
    __shared__ float s_pre[G4];
    __shared__ float s_in[2][G4];                   // L1 staged pre1 (dbuf)
    __shared__ float xr[2];                         // L0 x dbuf
    __shared__ u32 hpbuf[2][100];                   // pre1-stage h0 dbuf

    // ================= pre1 streaming stage =================
    if (role >= 2) {
        const int q = role - 2;
        const int rl = tid >> 2, kq = tid & 3;
        u32 wp[25]; float bs = 0.f; int grow = 0;
        if (tid < 800) {
            grow = q * 200 + rl;
            const float* wr = Wih1 + (size_t)grow * HH + kq * 50;
            #pragma unroll
            for (int i = 0; i < 25; ++i) wp[i] = pkh(wr[2*i], wr[2*i+1]);
            #pragma unroll
            for (int i = 0; i < 25; ++i) asm volatile("" : "+v"(wp[i]));
            if (kq == 0) bs = bih1[grow] + bhh1[grow];
        } else if (tid >= 832 && tid < 932) {
            hpbuf[0][tid - 832] = poll1u(&hp0[tid - 832], 1u);  // preload h0[0]
        }
        u32 prog_c = 0;
        __syncthreads();
        for (int t = 0; t < TT; ++t) {
            if (tid < 800) {
                const u32* hb = hpbuf[t & 1] + kq * 25;
                float a0 = 0.f, a1 = 0.f;
                #pragma unroll
                for (int i = 0; i < 25; i += 2) a0 = dot2(wp[i], hb[i], a0);
                #pragma unroll
                for (int i = 1; i < 25; i += 2) a1 = dot2(wp[i], hb[i], a1);
                float s = a0 + a1;
                s += __shfl_xor(s, 1);
                s += __shfl_xor(s, 2);
                if (kq == 0)
                    ast(&p1r[(size_t)(t & RDM) * G4 + grow],
                        pckf((u32)(t + 1), s + bs));
            } else if (tid >= 832 && tid < 932) {
                if (t + 1 < TT)
                    hpbuf[(t + 1) & 1][tid - 832] =
                        poll1u(&hp0[(size_t)(t + 1) * 100 + (tid - 832)],
                               (u32)(t + 2));
            } else if (tid == 1008) {
                while ((int)(t + 1) - (int)prog_c >= BPWIN) {
                    __builtin_amdgcn_s_sleep(8);
                    prog_c = __hip_atomic_load(prog, __ATOMIC_RELAXED,
                                               __HIP_MEMORY_SCOPE_AGENT);
                }
            }
            __syncthreads();
        }
        return;
    }

    // ================= recurrence stages (1 CU each) =================
    const bool L0 = (role == 0);
    const float* Whh = L0 ? Whh0 : Whh1;

    // LDS weight tier: pairs p in [0,36) -> cols [0,72)
    for (int idx = tid; idx < G4 * 36; idx += 1024) {
        const int r = idx / 36, p = idx % 36;
        const float* wr = Whh + (size_t)r * HH;
        wl[(((p >> 2) * G4 + r) << 2) + (p & 3)] = pkh(wr[2*p], wr[2*p + 1]);
    }
    // reg weight tier: pairs 36+i -> cols [72,200)
    u32 w[NWR]; float wih = 0.f, bs = 0.f;
    if (tid < G4) {
        const float* wr = Whh + (size_t)tid * HH + 72;
        #pragma unroll
        for (int i = 0; i < NWR; ++i) w[i] = pkh(wr[2*i], wr[2*i + 1]);
        #pragma unroll
        for (int i = 0; i < NWR; ++i) asm volatile("" : "+v"(w[i]));
        if (L0) {
            bs = bih0[tid] + bhh0[tid];
            wih = Wih0[tid];
            asm volatile("" : "+v"(bs));
            asm volatile("" : "+v"(wih));
        }
    }
    if (tid < 100) { hp_lds[0][tid] = 0u; hp_lds[1][tid] = 0u; }
    if (tid < HH) h32[tid] = 0.f;

    float c = 0.f, c2 = 0.f;
    float o0=0.f, o1=0.f, o2=0.f, o3=0.f, o4=0.f;
    if (!L0 && tid >= 832) {        // preload pre1[0] into s_in[0]
        float o[5];
        poll5(p1r, 1u, tid - 832, o);
        const int m = tid - 832;
        s_in[0][m] = o[0]; s_in[0][m+192] = o[1]; s_in[0][m+384] = o[2];
        s_in[0][m+576] = o[3];
        if (m < 32) s_in[0][m+768] = o[4];
    }
    if (L0 && tid == 832) xr[0] = x[0];
    __syncthreads();

    for (int t = 0; t < TT; ++t) {
        const int p = t & 1;
        // ---- phase A: primaries FMA; service waves fetch next input ----
        if (tid < G4) {
            const uint4* hp4 = (const uint4*)hp_lds[p];
            float a0=0.f, a1=0.f, a2=0.f, a3=0.f;
            #pragma unroll
            for (int j = 0; j < NLJ; ++j) {
                const uint4 hu = hp4[j];
                const uint4 wu = *(const uint4*)&wl[(j * G4 + tid) << 2];
                a0 = dot2(wu.x, hu.x, a0);
                a1 = dot2(wu.y, hu.y, a1);
                a2 = dot2(wu.z, hu.z, a2);
                a3 = dot2(wu.w, hu.w, a3);
                if ((j % 3) == 2) __builtin_amdgcn_sched_barrier(0);
            }
            #pragma unroll
            for (int j = NLJ; j < 25; ++j) {
                const uint4 hu = hp4[j];
                const int i = (j - NLJ) * 4;
                a0 = dot2(w[i],     hu.x, a0);
                a1 = dot2(w[i + 1], hu.y, a1);
                a2 = dot2(w[i + 2], hu.z, a2);
                a3 = dot2(w[i + 3], hu.w, a3);
                if ((j % 4) == 3) __builtin_amdgcn_sched_barrier(0);
            }
            const float acc = (a0 + a1) + (a2 + a3);
            if (L0) s_pre[tid] = acc + xr[p] * wih + bs;
            else    s_pre[tid] = acc + s_in[p][tid];
        } else if (tid >= 832) {
            if (!L0) {
                if (t + 1 < TT) {
                    float o[5];
                    poll5(&p1r[(size_t)((t + 1) & RDM) * G4], (u32)(t + 2),
                          tid - 832, o);
                    o0=o[0]; o1=o[1]; o2=o[2]; o3=o[3]; o4=o[4];
                }
            } else if (tid == 832 && t + 1 < TT) {
                o0 = x[t + 1];
            }
        }
        __syncthreads();
        // ---- phase B: gates + h-pack + restage (service waves) ----
        if (tid >= 832) {
            const int n = tid - 832;
            const float ig = sigmoidf_(s_pre[n]);
            const float fg = sigmoidf_(s_pre[200 + n]);
            const float gg = tanhf_  (s_pre[400 + n]);
            const float og = sigmoidf_(s_pre[600 + n]);
            c = fg * c + ig * gg;
            const float h = og * tanhf_(c);
            h32[n] = h;
            const float hpart = __shfl_xor(h, 1);
            u32 pk2 = 0;
            if (!(n & 1)) { pk2 = pkh(h, hpart); hp_lds[p ^ 1][n >> 1] = pk2; }
            float h2 = 0.f;
            if (n < 8) {
                const int n2 = 192 + n;
                const float ig2 = sigmoidf_(s_pre[n2]);
                const float fg2 = sigmoidf_(s_pre[200 + n2]);
                const float gg2 = tanhf_  (s_pre[400 + n2]);
                const float og2 = sigmoidf_(s_pre[600 + n2]);
                c2 = fg2 * c2 + ig2 * gg2;
                h2 = og2 * tanhf_(c2);
                h32[n2] = h2;
            }
            const float h2part = __shfl_xor(h2, 1);
            u32 pk2b = 0;
            if (n < 8 && !(n & 1)) { pk2b = pkh(h2, h2part); hp_lds[p ^ 1][96 + (n>>1)] = pk2b; }
            if (L0 && !(n & 1)) {
                ast(&hp0[(size_t)t * 100 + (n >> 1)], pcku((u32)(t + 1), pk2));
                if (n < 8)
                    ast(&hp0[(size_t)t * 100 + 96 + (n >> 1)],
                        pcku((u32)(t + 1), pk2b));
            }
            if (t + 1 < TT) {
                if (!L0) {          // restage next pre1 into s_in[p^1]
                    const int m = n;
                    s_in[p ^ 1][m] = o0; s_in[p ^ 1][m + 192] = o1;
                    s_in[p ^ 1][m + 384] = o2; s_in[p ^ 1][m + 576] = o3;
                    if (m < 32) s_in[p ^ 1][m + 768] = o4;
                } else if (tid == 832) {
                    xr[p ^ 1] = o0;
                }
            }
        } else if (!L0 && tid == 800 && (t & 63) == 63) {
            __hip_atomic_store(prog, (u32)(t + 1), __ATOMIC_RELAXED,
                               __HIP_MEMORY_SCOPE_AGENT);
        }
        __syncthreads();
    }

    // ---- linear head on final h1 (L1 block) ----
    if (!L0 && tid < 64) {
        float s2 = 0.f;
        for (int k = tid; k < HH; k += 64) s2 += h32[k] * Wout[k];
        #pragma unroll
        for (int off = 32; off > 0; off >>= 1) s2 += __shfl_down(s2, off);
        if (tid == 0) out[0] = s2 + bout[0];
    }
}

extern "C" void kernel_launch(void* const* d_in, const int* in_sizes, int n_in,
                              void* d_out, int out_size, void* d_ws, size_t ws_size,
                              hipStream_t stream) {
    const float* x    = (const float*)d_in[0];
    const float* Wih0 = (const float*)d_in[1];
    const float* Whh0 = (const float*)d_in[2];
    const float* bih0 = (const float*)d_in[3];
    const float* bhh0 = (const float*)d_in[4];
    const float* Wih1 = (const float*)d_in[5];
    const float* Whh1 = (const float*)d_in[6];
    const float* bih1 = (const float*)d_in[7];
    const float* bhh1 = (const float*)d_in[8];
    const float* Wout = (const float*)d_in[9];
    const float* bout = (const float*)d_in[10];
    float* out = (float*)d_out;

    char* ws = (char*)d_ws;
    // hp0 6,553,600 | p1r 6,553,600 | prog 64
    u64* hp0  = (u64*)ws;
    u64* p1r  = (u64*)(ws + 6553600);
    u32* prog = (u32*)(ws + 13107200);

    // clear all tags/progress every launch (graph-safe, deterministic)
    hipMemsetAsync(ws, 0, 13107264, stream);

    hipLaunchKernelGGL(lstm_pipe, dim3(6), dim3(1024), 0, stream,
        x, Wih0, Whh0, bih0, bhh0, Wih1, Whh1, bih1, bhh1, Wout, bout,
        hp0, p1r, prog, out);
}

// Round 8
// 14842.110 us; speedup vs baseline: 1.7766x; 1.0209x over previous
//
#include <hip/hip_runtime.h>

#define TT 8192
#define HH 200
#define G4 800
#define NLJ 6       // LDS-tier uint4 groups/row (24 pairs = cols 0..47)
#define NWR 76      // reg-tier pairs/row (cols 48..199)
#define RD 1024     // pre1 ring depth (steps)
#define RDM 1023
#define BPWIN 900

typedef unsigned long long u64;
typedef unsigned int u32;
typedef _Float16 f16;
typedef _Float16 f16x2 __attribute__((ext_vector_type(2)));

__device__ __forceinline__ float sigmoidf_(float x){ return 1.0f/(1.0f+__expf(-x)); }
__device__ __forceinline__ float tanhf_(float x){
    float e = __expf(2.0f*fabsf(x));
    float r = 1.0f - 2.0f/(e + 1.0f);
    return copysignf(r, x);
}
__device__ __forceinline__ u64 pcku(u32 tag, u32 v){ return ((u64)tag<<32) | v; }
__device__ __forceinline__ u64 pckf(u32 tag, float v){ return pcku(tag, __float_as_uint(v)); }
__device__ __forceinline__ u64 ald(const u64* p){
    return __hip_atomic_load((u64*)p, __ATOMIC_RELAXED, __HIP_MEMORY_SCOPE_AGENT);
}
__device__ __forceinline__ void ast(u64* p, u64 v){
    __hip_atomic_store(p, v, __ATOMIC_RELAXED, __HIP_MEMORY_SCOPE_AGENT);
}
__device__ __forceinline__ u32 pkh(float a, float b){   // fp32x2 -> packed f16 (RNE)
    f16x2 v = { (f16)a, (f16)b };
    return __builtin_bit_cast(u32, v);
}
__device__ __forceinline__ float dot2(u32 a, u32 b, float c){
#if __has_builtin(__builtin_amdgcn_fdot2)
    return __builtin_amdgcn_fdot2(__builtin_bit_cast(f16x2, a),
                                  __builtin_bit_cast(f16x2, b), c, false);
#else
    f16x2 av = __builtin_bit_cast(f16x2, a), bv = __builtin_bit_cast(f16x2, b);
    return c + (float)av[0]*(float)bv[0] + (float)av[1]*(float)bv[1];
#endif
}
__device__ __forceinline__ u32 poll1u(const u64* p, u32 tag){
    u64 v; do { v = ald(p); } while ((u32)(v >> 32) != tag);
    return (u32)v;
}
// 192 lanes (m = tid-832) fetch 800 tagged fp32 values, loads batched in flight
__device__ __forceinline__ void poll5(const u64* slot, u32 tag, int m, float* o){
    const bool g4 = (m < 32);
    u64 v0, v1, v2, v3, v4 = 0;
    for(;;){
        v0 = ald(slot + m);       v1 = ald(slot + m + 192);
        v2 = ald(slot + m + 384); v3 = ald(slot + m + 576);
        if (g4) v4 = ald(slot + m + 768);
        if ((u32)(v0>>32)==tag && (u32)(v1>>32)==tag && (u32)(v2>>32)==tag &&
            (u32)(v3>>32)==tag && (!g4 || (u32)(v4>>32)==tag)) break;
    }
    o[0]=__uint_as_float((u32)v0); o[1]=__uint_as_float((u32)v1);
    o[2]=__uint_as_float((u32)v2); o[3]=__uint_as_float((u32)v3);
    o[4]= g4 ? __uint_as_float((u32)v4) : 0.f;
}

// roles: 0 = layer-0 recurrence, 1 = layer-1 recurrence, 2..5 = pre1 (gate q).
// Recurrence CU: 800 primaries (waves 0-12) each own one gate row, 100 f16-pair
// dot2/step (76 pairs VGPR, 24 pairs LDS). Service waves 13-15: polls + gates +
// restage. 2 barriers/step via s_in/hp_lds/xr double-buffers.
// amdgpu_waves_per_eu(4,4): pins the allocator's occupancy target to what the
// LDS footprint already forces (1 block/CU = 4 waves/EU) -> 128-VGPR budget.
// Rounds 2/5/6/7 showed the default heuristic ignores LDS and targets 8/EU
// -> 64-reg budget -> per-step scratch spill reloads (the hidden 2000 cyc).
__global__ __launch_bounds__(1024)
__attribute__((amdgpu_waves_per_eu(4, 4)))
void lstm_pipe(const float* __restrict__ x,
               const float* __restrict__ Wih0, const float* __restrict__ Whh0,
               const float* __restrict__ bih0, const float* __restrict__ bhh0,
               const float* __restrict__ Wih1, const float* __restrict__ Whh1,
               const float* __restrict__ bih1, const float* __restrict__ bhh1,
               const float* __restrict__ Wout, const float* __restrict__ bout,
               u64* __restrict__ hp0,   // [TT][100] tagged packed-f16 h0 pairs
               u64* __restrict__ p1r,   // [RD][G4] tagged fp32 ring
               u32* __restrict__ prog,  // [1] layer-1 progress
               float* __restrict__ out)
{
    const int role = blockIdx.x;
    const int tid  = threadIdx.x;

    __shared__ __align__(16) u32 wl[NLJ * G4 * 4];  // 76,800B
    __shared__ __align__(16) u32 hp_lds[2][100];    // packed h pairs (dbuf)
    __shared__ float h32[HH];
    __shared__ float s_pre[G4];
    __shared__ float s_in[2][G4];                   // L1 staged pre1 (dbuf)
    __shared__ float xr[2];                         // L0 x dbuf
    __shared__ u32 hpbuf[2][100];                   // pre1-stage h0 dbuf

    // ================= pre1 streaming stage =================
    if (role >= 2) {
        const int q = role - 2;
        const int rl = tid >> 2, kq = tid & 3;
        u32 wp[25]; float bs = 0.f; int grow = 0;
        if (tid < 800) {
            grow = q * 200 + rl;
            const float* wr = Wih1 + (size_t)grow * HH + kq * 50;
            #pragma unroll
            for (int i = 0; i < 25; ++i) wp[i] = pkh(wr[2*i], wr[2*i+1]);
            #pragma unroll
            for (int i = 0; i < 25; ++i) asm volatile("" : "+v"(wp[i]));
            if (kq == 0) bs = bih1[grow] + bhh1[grow];
        } else if (tid >= 832 && tid < 932) {
            hpbuf[0][tid - 832] = poll1u(&hp0[tid - 832], 1u);  // preload h0[0]
        }
        u32 prog_c = 0;
        __syncthreads();
        for (int t = 0; t < TT; ++t) {
            if (tid < 800) {
                const u32* hb = hpbuf[t & 1] + kq * 25;
                float a0 = 0.f, a1 = 0.f;
                #pragma unroll
                for (int i = 0; i < 25; i += 2) a0 = dot2(wp[i], hb[i], a0);
                #pragma unroll
                for (int i = 1; i < 25; i += 2) a1 = dot2(wp[i], hb[i], a1);
                float s = a0 + a1;
                s += __shfl_xor(s, 1);
                s += __shfl_xor(s, 2);
                if (kq == 0)
                    ast(&p1r[(size_t)(t & RDM) * G4 + grow],
                        pckf((u32)(t + 1), s + bs));
            } else if (tid >= 832 && tid < 932) {
                if (t + 1 < TT)
                    hpbuf[(t + 1) & 1][tid - 832] =
                        poll1u(&hp0[(size_t)(t + 1) * 100 + (tid - 832)],
                               (u32)(t + 2));
            } else if (tid == 1008) {
                while ((int)(t + 1) - (int)prog_c >= BPWIN) {
                    __builtin_amdgcn_s_sleep(8);
                    prog_c = __hip_atomic_load(prog, __ATOMIC_RELAXED,
                                               __HIP_MEMORY_SCOPE_AGENT);
                }
            }
            __syncthreads();
        }
        return;
    }

    // ================= recurrence stages (1 CU each) =================
    const bool L0 = (role == 0);
    const float* Whh = L0 ? Whh0 : Whh1;

    // LDS weight tier: pairs p in [0,24) -> cols [0,48)
    for (int idx = tid; idx < G4 * 24; idx += 1024) {
        const int r = idx / 24, p = idx % 24;
        const float* wr = Whh + (size_t)r * HH;
        wl[(((p >> 2) * G4 + r) << 2) + (p & 3)] = pkh(wr[2*p], wr[2*p + 1]);
    }
    // reg weight tier: pairs 24+i -> cols [48,200)
    u32 w[NWR]; float wih = 0.f, bs = 0.f;
    if (tid < G4) {
        const float* wr = Whh + (size_t)tid * HH + 48;
        #pragma unroll
        for (int i = 0; i < NWR; ++i) w[i] = pkh(wr[2*i], wr[2*i + 1]);
        #pragma unroll
        for (int i = 0; i < NWR; ++i) asm volatile("" : "+v"(w[i]));
        if (L0) {
            bs = bih0[tid] + bhh0[tid];
            wih = Wih0[tid];
            asm volatile("" : "+v"(bs));
            asm volatile("" : "+v"(wih));
        }
    }
    if (tid < 100) { hp_lds[0][tid] = 0u; hp_lds[1][tid] = 0u; }
    if (tid < HH) h32[tid] = 0.f;

    float c = 0.f, c2 = 0.f;
    float o0=0.f, o1=0.f, o2=0.f, o3=0.f, o4=0.f;
    if (!L0 && tid >= 832) {        // preload pre1[0] into s_in[0]
        float o[5];
        poll5(p1r, 1u, tid - 832, o);
        const int m = tid - 832;
        s_in[0][m] = o[0]; s_in[0][m+192] = o[1]; s_in[0][m+384] = o[2];
        s_in[0][m+576] = o[3];
        if (m < 32) s_in[0][m+768] = o[4];
    }
    if (L0 && tid == 832) xr[0] = x[0];
    __syncthreads();

    for (int t = 0; t < TT; ++t) {
        const int p = t & 1;
        // ---- phase A: primaries FMA; service waves fetch next input ----
        if (tid < G4) {
            const uint4* hp4 = (const uint4*)hp_lds[p];
            float a0=0.f, a1=0.f, a2=0.f, a3=0.f;
            #pragma unroll
            for (int j = 0; j < NLJ; ++j) {
                const uint4 hu = hp4[j];
                const uint4 wu = *(const uint4*)&wl[(j * G4 + tid) << 2];
                a0 = dot2(wu.x, hu.x, a0);
                a1 = dot2(wu.y, hu.y, a1);
                a2 = dot2(wu.z, hu.z, a2);
                a3 = dot2(wu.w, hu.w, a3);
                if ((j % 3) == 2) __builtin_amdgcn_sched_barrier(0);
            }
            #pragma unroll
            for (int j = NLJ; j < 25; ++j) {
                const uint4 hu = hp4[j];
                const int i = (j - NLJ) * 4;
                a0 = dot2(w[i],     hu.x, a0);
                a1 = dot2(w[i + 1], hu.y, a1);
                a2 = dot2(w[i + 2], hu.z, a2);
                a3 = dot2(w[i + 3], hu.w, a3);
                if ((j % 4) == 3) __builtin_amdgcn_sched_barrier(0);
            }
            const float acc = (a0 + a1) + (a2 + a3);
            if (L0) s_pre[tid] = acc + xr[p] * wih + bs;
            else    s_pre[tid] = acc + s_in[p][tid];
        } else if (tid >= 832) {
            if (!L0) {
                if (t + 1 < TT) {
                    float o[5];
                    poll5(&p1r[(size_t)((t + 1) & RDM) * G4], (u32)(t + 2),
                          tid - 832, o);
                    o0=o[0]; o1=o[1]; o2=o[2]; o3=o[3]; o4=o[4];
                }
            } else if (tid == 832 && t + 1 < TT) {
                o0 = x[t + 1];
            }
        }
        __syncthreads();
        // ---- phase B: gates + h-pack + restage (service waves) ----
        if (tid >= 832) {
            const int n = tid - 832;
            const float ig = sigmoidf_(s_pre[n]);
            const float fg = sigmoidf_(s_pre[200 + n]);
            const float gg = tanhf_  (s_pre[400 + n]);
            const float og = sigmoidf_(s_pre[600 + n]);
            c = fg * c + ig * gg;
            const float h = og * tanhf_(c);
            h32[n] = h;
            const float hpart = __shfl_xor(h, 1);
            u32 pk2 = 0;
            if (!(n & 1)) { pk2 = pkh(h, hpart); hp_lds[p ^ 1][n >> 1] = pk2; }
            float h2 = 0.f;
            if (n < 8) {
                const int n2 = 192 + n;
                const float ig2 = sigmoidf_(s_pre[n2]);
                const float fg2 = sigmoidf_(s_pre[200 + n2]);
                const float gg2 = tanhf_  (s_pre[400 + n2]);
                const float og2 = sigmoidf_(s_pre[600 + n2]);
                c2 = fg2 * c2 + ig2 * gg2;
                h2 = og2 * tanhf_(c2);
                h32[n2] = h2;
            }
            const float h2part = __shfl_xor(h2, 1);
            u32 pk2b = 0;
            if (n < 8 && !(n & 1)) { pk2b = pkh(h2, h2part); hp_lds[p ^ 1][96 + (n>>1)] = pk2b; }
            if (L0 && !(n & 1)) {
                ast(&hp0[(size_t)t * 100 + (n >> 1)], pcku((u32)(t + 1), pk2));
                if (n < 8)
                    ast(&hp0[(size_t)t * 100 + 96 + (n >> 1)],
                        pcku((u32)(t + 1), pk2b));
            }
            if (t + 1 < TT) {
                if (!L0) {          // restage next pre1 into s_in[p^1]
                    const int m = n;
                    s_in[p ^ 1][m] = o0; s_in[p ^ 1][m + 192] = o1;
                    s_in[p ^ 1][m + 384] = o2; s_in[p ^ 1][m + 576] = o3;
                    if (m < 32) s_in[p ^ 1][m + 768] = o4;
                } else if (tid == 832) {
                    xr[p ^ 1] = o0;
                }
            }
        } else if (!L0 && tid == 800 && (t & 63) == 63) {
            __hip_atomic_store(prog, (u32)(t + 1), __ATOMIC_RELAXED,
                               __HIP_MEMORY_SCOPE_AGENT);
        }
        __syncthreads();
    }

    // ---- linear head on final h1 (L1 block) ----
    if (!L0 && tid < 64) {
        float s2 = 0.f;
        for (int k = tid; k < HH; k += 64) s2 += h32[k] * Wout[k];
        #pragma unroll
        for (int off = 32; off > 0; off >>= 1) s2 += __shfl_down(s2, off);
        if (tid == 0) out[0] = s2 + bout[0];
    }
}

extern "C" void kernel_launch(void* const* d_in, const int* in_sizes, int n_in,
                              void* d_out, int out_size, void* d_ws, size_t ws_size,
                              hipStream_t stream) {
    const float* x    = (const float*)d_in[0];
    const float* Wih0 = (const float*)d_in[1];
    const float* Whh0 = (const float*)d_in[2];
    const float* bih0 = (const float*)d_in[3];
    const float* bhh0 = (const float*)d_in[4];
    const float* Wih1 = (const float*)d_in[5];
    const float* Whh1 = (const float*)d_in[6];
    const float* bih1 = (const float*)d_in[7];
    const float* bhh1 = (const float*)d_in[8];
    const float* Wout = (const float*)d_in[9];
    const float* bout = (const float*)d_in[10];
    float* out = (float*)d_out;

    char* ws = (char*)d_ws;
    // hp0 6,553,600 | p1r 6,553,600 | prog 64
    u64* hp0  = (u64*)ws;
    u64* p1r  = (u64*)(ws + 6553600);
    u32* prog = (u32*)(ws + 13107200);

    // clear all tags/progress every launch (graph-safe, deterministic)
    hipMemsetAsync(ws, 0, 13107264, stream);

    hipLaunchKernelGGL(lstm_pipe, dim3(6), dim3(1024), 0, stream,
        x, Wih0, Whh0, bih0, bhh0, Wih1, Whh1, bih1, bhh1, Wout, bout,
        hp0, p1r, prog, out);
}

// Round 9
// 14701.559 us; speedup vs baseline: 1.7936x; 1.0096x over previous
//
#include <hip/hip_runtime.h>

#define TT 8192
#define HH 200
#define RD 1024     // pre1 ring depth (steps)
#define RDM 1023
#define BPWIN 900

typedef unsigned long long u64;
typedef unsigned int u32;
typedef _Float16 f16;
typedef _Float16 f16x2 __attribute__((ext_vector_type(2)));

__device__ __forceinline__ float sigmoidf_(float x){ return 1.0f/(1.0f+__expf(-x)); }
__device__ __forceinline__ float tanhf_(float x){
    float e = __expf(2.0f*fabsf(x));
    float r = 1.0f - 2.0f/(e + 1.0f);
    return copysignf(r, x);
}
__device__ __forceinline__ u64 pcku(u32 tag, u32 v){ return ((u64)tag<<32) | v; }
__device__ __forceinline__ u64 pckf(u32 tag, float v){ return pcku(tag, __float_as_uint(v)); }
__device__ __forceinline__ u64 ald(const u64* p){
    return __hip_atomic_load((u64*)p, __ATOMIC_RELAXED, __HIP_MEMORY_SCOPE_AGENT);
}
__device__ __forceinline__ void ast(u64* p, u64 v){
    __hip_atomic_store(p, v, __ATOMIC_RELAXED, __HIP_MEMORY_SCOPE_AGENT);
}
__device__ __forceinline__ u32 pkh(float a, float b){   // fp32x2 -> packed f16 RNE
    f16x2 v = { (f16)a, (f16)b };
    return __builtin_bit_cast(u32, v);
}
__device__ __forceinline__ float unpk(u32 u, int hi){
    f16x2 v = __builtin_bit_cast(f16x2, u);
    return (float)v[hi];
}
__device__ __forceinline__ float dot2(u32 a, u32 b, float c){
#if __has_builtin(__builtin_amdgcn_fdot2)
    return __builtin_amdgcn_fdot2(__builtin_bit_cast(f16x2, a),
                                  __builtin_bit_cast(f16x2, b), c, false);
#else
    f16x2 av = __builtin_bit_cast(f16x2, a), bv = __builtin_bit_cast(f16x2, b);
    return c + (float)av[0]*(float)bv[0] + (float)av[1]*(float)bv[1];
#endif
}
__device__ __forceinline__ u32 poll1u(const u64* p, u32 tag){
    u64 v; do { v = ald(p); } while ((u32)(v >> 32) != tag);
    return (u32)v;
}

// 64 lanes fetch 100 tagged slots (lane l gets l and l+64 if <100)
__device__ __forceinline__ void poll100(const u64* base, u32 tag, int l,
                                        u32* o0, u32* o1){
    const bool g1 = (l + 64 < 100);
    u64 v0, v1 = 0;
    for(;;){
        v0 = ald(base + l);
        if (g1) v1 = ald(base + l + 64);
        if ((u32)(v0>>32)==tag && (!g1 || (u32)(v1>>32)==tag)) break;
    }
    *o0 = (u32)v0;
    *o1 = (u32)v1;
}

// Grid of 16 (bid%8 -> XCD): pairs (0,8)=L0 halves, (1,9)=L1 halves,
// (2,10,3,11)=pre1 gates 0..3, rest exit. 512 threads/block: at this shape
// the allocator's VGPR budget is 128 (r2-r4 evidence) so the 88-pair reg
// tier (+~24 working) is truly resident -- the r5-r8 1024-thread shape was
// hard-capped at 64 and spilled to L2 scratch (~3100 cyc/step, the bottleneck).
__global__ __launch_bounds__(512)
__attribute__((amdgpu_waves_per_eu(2, 4)))
void lstm_pipe(const float* __restrict__ x,
               const float* __restrict__ Wih0, const float* __restrict__ Whh0,
               const float* __restrict__ bih0, const float* __restrict__ bhh0,
               const float* __restrict__ Wih1, const float* __restrict__ Whh1,
               const float* __restrict__ bih1, const float* __restrict__ bhh1,
               const float* __restrict__ Wout, const float* __restrict__ bout,
               u64* __restrict__ hp0,   // [TT][100] tagged packed-f16 h0 pairs
               u64* __restrict__ p1r,   // [RD][800] tagged fp32 ring
               u64* __restrict__ h1x,   // [64][100] tagged packed-f16 h1 pairs
               u32* __restrict__ prog,  // [1] layer-1 progress
               float* __restrict__ out)
{
    const int bid = blockIdx.x;
    const int tid = threadIdx.x;

    __shared__ __align__(16) u32 wl[3 * 400 * 4];   // 19,200B LDS weight tier
    __shared__ float xs[TT];                        // 32,768B (L0 only)
    __shared__ __align__(16) u32 hp_lds[2][100];    // packed h pairs (dbuf)
    __shared__ u32 hpbuf[2][100];                   // pre1 h0 dbuf
    __shared__ float s_pre[400];
    __shared__ float s_in[2][400];                  // L1 staged pre1 (dbuf)
    __shared__ float h32[100];
    __shared__ float pad_f[6656];                   // 26,624B -> 1 block/CU

    if (x == nullptr) pad_f[0] = 1.f;               // keep pad allocated

    // role decode
    int role = -1, L = 0, hf = 0, q = 0;
    if      (bid == 0)  { role = 0; L = 0; hf = 0; }
    else if (bid == 8)  { role = 0; L = 0; hf = 1; }
    else if (bid == 1)  { role = 0; L = 1; hf = 0; }
    else if (bid == 9)  { role = 0; L = 1; hf = 1; }
    else if (bid == 2)  { role = 1; q = 0; }
    else if (bid == 10) { role = 1; q = 1; }
    else if (bid == 3)  { role = 1; q = 2; }
    else if (bid == 11) { role = 1; q = 3; }
    if (role < 0) return;

    // ================= pre1 streaming stage =================
    if (role == 1) {
        const int rl = tid >> 1, kh = tid & 1;      // row 0..199, col-half
        const bool act = (tid < 400);
        u32 wp[50]; float bs = 0.f; int row = 0;
        if (act) {
            row = q * 200 + rl;
            const float* wr = Wih1 + (size_t)row * HH + kh * 100;
            #pragma unroll
            for (int i = 0; i < 50; ++i) wp[i] = pkh(wr[2*i], wr[2*i+1]);
            #pragma unroll
            for (int i = 0; i < 50; ++i) asm volatile("" : "+v"(wp[i]));
            if (kh == 0) bs = bih1[row] + bhh1[row];
        } else if (tid >= 448) {                    // preload h0[0]
            u32 o0, o1;
            poll100(hp0, 1u, tid - 448, &o0, &o1);
            hpbuf[0][tid - 448] = o0;
            if (tid - 448 + 64 < 100) hpbuf[0][tid - 448 + 64] = o1;
        }
        u32 prog_c = 0;
        __syncthreads();
        for (int t = 0; t < TT; ++t) {
            if (act) {
                const u32* hb = hpbuf[t & 1] + kh * 50;
                float a0 = 0.f, a1 = 0.f;
                #pragma unroll
                for (int i = 0; i < 50; i += 2) a0 = dot2(wp[i], hb[i], a0);
                #pragma unroll
                for (int i = 1; i < 50; i += 2) a1 = dot2(wp[i], hb[i], a1);
                float s = a0 + a1;
                s += __shfl_xor(s, 1);
                if (kh == 0)
                    ast(&p1r[(size_t)(t & RDM) * 800 + q * 200 + rl],
                        pckf((u32)(t + 1), s + bs));
            } else if (tid >= 448) {
                if (t + 1 < TT) {
                    u32 o0, o1;
                    poll100(&hp0[(size_t)(t + 1) * 100], (u32)(t + 2),
                            tid - 448, &o0, &o1);
                    hpbuf[(t + 1) & 1][tid - 448] = o0;
                    if (tid - 448 + 64 < 100) hpbuf[(t + 1) & 1][tid - 448 + 64] = o1;
                }
            } else if (tid == 440) {
                while ((int)(t + 1) - (int)prog_c >= BPWIN) {
                    __builtin_amdgcn_s_sleep(8);
                    prog_c = __hip_atomic_load(prog, __ATOMIC_RELAXED,
                                               __HIP_MEMORY_SCOPE_AGENT);
                }
            }
            __syncthreads();
        }
        return;
    }

    // ================= recurrence half-blocks =================
    const int nb = hf * 100;                 // own neuron base
    const int pb = (1 - hf) * 100;           // partner neuron base (cols)
    const float* Whh = L ? Whh1 : Whh0;
    const bool act = (tid < 400);

    // LDS weight tier: pairs 0..11 (cols 0..23)
    for (int idx = tid; idx < 400 * 12; idx += 512) {
        const int rl = idx / 12, pp = idx % 12;
        const int row = (rl / 100) * 200 + nb + (rl % 100);
        wl[(((pp >> 2) * 400) + rl) * 4 + (pp & 3)] =
            pkh(Whh[(size_t)row * HH + 2*pp], Whh[(size_t)row * HH + 2*pp + 1]);
    }
    // reg weight tier: pairs 12..99 (cols 24..199)
    u32 w[88]; float wih = 0.f, bs = 0.f;
    if (act) {
        const int row = (tid / 100) * 200 + nb + (tid % 100);
        const float* wr = Whh + (size_t)row * HH + 24;
        #pragma unroll
        for (int i = 0; i < 88; ++i) w[i] = pkh(wr[2*i], wr[2*i + 1]);
        #pragma unroll
        for (int i = 0; i < 88; ++i) asm volatile("" : "+v"(w[i]));
        if (L == 0) {
            bs = bih0[row] + bhh0[row];
            wih = Wih0[row];
            asm volatile("" : "+v"(bs));
            asm volatile("" : "+v"(wih));
        }
    }
    if (L == 0) for (int i = tid; i < TT; i += 512) xs[i] = x[i];
    if (tid < 100) { hp_lds[0][tid] = 0u; hp_lds[1][tid] = 0u; h32[tid] = 0.f; }

    // L1: preload pre1[0] into s_in[0] (wave 7; 7 slots in flight per lane)
    u32 ov[7];
    if (L == 1 && tid >= 448) {
        const int l = tid - 448;
        int sl[7]; bool g[7];
        #pragma unroll
        for (int r = 0; r < 7; ++r) {
            const int m = l + 64 * r;
            g[r] = (m < 400);
            sl[r] = g[r] ? (m / 100) * 200 + nb + (m % 100) : 0;
        }
        u64 v[7];
        for(;;){
            #pragma unroll
            for (int r = 0; r < 7; ++r) if (g[r]) v[r] = ald(&p1r[sl[r]]);
            bool ok = true;
            #pragma unroll
            for (int r = 0; r < 7; ++r) if (g[r] && (u32)(v[r]>>32) != 1u) ok = false;
            if (ok) break;
        }
        #pragma unroll
        for (int r = 0; r < 7; ++r)
            if (g[r]) s_in[0][l + 64 * r] = __uint_as_float((u32)v[r]);
    }
    float c = 0.f;
    __syncthreads();

    for (int t = 0; t < TT; ++t) {
        const int p = t & 1;
        // ---- phase A: FMA; L1 wave 7 prefetches pre1[t+1] into regs ----
        if (act) {
            const uint4* hp4 = (const uint4*)hp_lds[p];
            float a0=0.f, a1=0.f, a2=0.f, a3=0.f;
            #pragma unroll
            for (int g2 = 0; g2 < 3; ++g2) {
                const uint4 hu = hp4[g2];
                const uint4 wu = *(const uint4*)&wl[((g2 * 400) + tid) << 2];
                a0 = dot2(wu.x, hu.x, a0);
                a1 = dot2(wu.y, hu.y, a1);
                a2 = dot2(wu.z, hu.z, a2);
                a3 = dot2(wu.w, hu.w, a3);
            }
            #pragma unroll
            for (int g2 = 3; g2 < 25; ++g2) {
                const uint4 hu = hp4[g2];
                const int i = (g2 - 3) * 4;
                a0 = dot2(w[i],     hu.x, a0);
                a1 = dot2(w[i + 1], hu.y, a1);
                a2 = dot2(w[i + 2], hu.z, a2);
                a3 = dot2(w[i + 3], hu.w, a3);
            }
            const float acc = (a0 + a1) + (a2 + a3);
            s_pre[tid] = acc + ((L == 0) ? xs[t] * wih + bs : s_in[p][tid]);
        } else if (L == 1 && tid >= 448 && t + 1 < TT) {
            const int l = tid - 448;
            u64 v[7];
            const u64* slot = &p1r[(size_t)((t + 1) & RDM) * 800];
            const u32 tg = (u32)(t + 2);
            for(;;){
                #pragma unroll
                for (int r = 0; r < 7; ++r) {
                    const int m = l + 64 * r;
                    if (m < 400) v[r] = ald(slot + (m/100)*200 + nb + (m%100));
                }
                bool ok = true;
                #pragma unroll
                for (int r = 0; r < 7; ++r) {
                    const int m = l + 64 * r;
                    if (m < 400 && (u32)(v[r]>>32) != tg) ok = false;
                }
                if (ok) break;
            }
            #pragma unroll
            for (int r = 0; r < 7; ++r) ov[r] = (u32)v[r];
        }
        __syncthreads();
        // ---- phase B: gates (lanes 0-99) || partner poll + restage (wave 7) ----
        if (tid < 100) {
            const int n = tid;
            const float ig = sigmoidf_(s_pre[n]);
            const float fg = sigmoidf_(s_pre[100 + n]);
            const float gg = tanhf_  (s_pre[200 + n]);
            const float og = sigmoidf_(s_pre[300 + n]);
            c = fg * c + ig * gg;
            const float h = og * tanhf_(c);
            h32[n] = h;
            const float hq = __shfl_xor(h, 1);
            if (!(n & 1)) {
                const u32 pk = pkh(h, hq);
                hp_lds[p ^ 1][(nb >> 1) + (n >> 1)] = pk;
                if (L == 0)
                    ast(&hp0[(size_t)t * 100 + (nb >> 1) + (n >> 1)],
                        pcku((u32)(t + 1), pk));
                else
                    ast(&h1x[(size_t)(t & 63) * 100 + (nb >> 1) + (n >> 1)],
                        pcku((u32)(t + 1), pk));
            }
        } else if (tid >= 448) {
            const int l = tid - 448;
            if (L == 1 && t + 1 < TT) {     // restage prefetched pre1
                #pragma unroll
                for (int r = 0; r < 7; ++r) {
                    const int m = l + 64 * r;
                    if (m < 400) s_in[p ^ 1][m] = __uint_as_float(ov[r]);
                }
            }
            if (l < 50) {                   // poll partner h[t]
                const u64* src = (L == 0)
                    ? &hp0[(size_t)t * 100 + (pb >> 1) + l]
                    : &h1x[(size_t)(t & 63) * 100 + (pb >> 1) + l];
                hp_lds[p ^ 1][(pb >> 1) + l] = poll1u(src, (u32)(t + 1));
            }
        } else if (L == 1 && hf == 0 && tid == 400 && (t & 63) == 63) {
            __hip_atomic_store(prog, (u32)(t + 1), __ATOMIC_RELAXED,
                               __HIP_MEMORY_SCOPE_AGENT);
        }
        __syncthreads();
    }

    // ---- linear head on final h1 (L1 half 0) ----
    if (L == 1 && hf == 0 && tid < 64) {
        const int fin = ((TT - 1) & 1) ^ 1;
        float s2 = 0.f;
        for (int k = tid; k < HH; k += 64) {
            float hv;
            if (k < 100) hv = h32[k];
            else         hv = unpk(hp_lds[fin][50 + ((k - 100) >> 1)], (k - 100) & 1);
            s2 += hv * Wout[k];
        }
        #pragma unroll
        for (int off = 32; off > 0; off >>= 1) s2 += __shfl_down(s2, off);
        if (tid == 0) out[0] = s2 + bout[0];
    }
}

extern "C" void kernel_launch(void* const* d_in, const int* in_sizes, int n_in,
                              void* d_out, int out_size, void* d_ws, size_t ws_size,
                              hipStream_t stream) {
    const float* x    = (const float*)d_in[0];
    const float* Wih0 = (const float*)d_in[1];
    const float* Whh0 = (const float*)d_in[2];
    const float* bih0 = (const float*)d_in[3];
    const float* bhh0 = (const float*)d_in[4];
    const float* Wih1 = (const float*)d_in[5];
    const float* Whh1 = (const float*)d_in[6];
    const float* bih1 = (const float*)d_in[7];
    const float* bhh1 = (const float*)d_in[8];
    const float* Wout = (const float*)d_in[9];
    const float* bout = (const float*)d_in[10];
    float* out = (float*)d_out;

    char* ws = (char*)d_ws;
    // hp0 6,553,600 | p1r 6,553,600 | h1x 51,200 | prog 64
    u64* hp0  = (u64*)ws;
    u64* p1r  = (u64*)(ws + 6553600);
    u64* h1x  = (u64*)(ws + 13107200);
    u32* prog = (u32*)(ws + 13158400);

    // clear all tags/progress every launch (graph-safe, deterministic)
    hipMemsetAsync(ws, 0, 13158464, stream);

    hipLaunchKernelGGL(lstm_pipe, dim3(16), dim3(512), 0, stream,
        x, Wih0, Whh0, bih0, bhh0, Wih1, Whh1, bih1, bhh1, Wout, bout,
        hp0, p1r, h1x, prog, out);
}

// Round 10
// 14162.399 us; speedup vs baseline: 1.8618x; 1.0381x over previous
//
#include <hip/hip_runtime.h>

#define TT 8192
#define HH 200
#define RD 1024     // pre1 ring depth (steps)
#define RDM 1023
#define BPWIN 900

typedef unsigned long long u64;
typedef unsigned int u32;
typedef _Float16 f16;
typedef _Float16 f16x2 __attribute__((ext_vector_type(2)));
typedef _Float16 half8 __attribute__((ext_vector_type(8)));
typedef float f32x4 __attribute__((ext_vector_type(4)));

__device__ __forceinline__ float sigmoidf_(float x){ return 1.0f/(1.0f+__expf(-x)); }
__device__ __forceinline__ float tanhf_(float x){
    float e = __expf(2.0f*fabsf(x));
    float r = 1.0f - 2.0f/(e + 1.0f);
    return copysignf(r, x);
}
__device__ __forceinline__ u64 pcku(u32 tag, u32 v){ return ((u64)tag<<32) | v; }
__device__ __forceinline__ u64 pckf(u32 tag, float v){ return pcku(tag, __float_as_uint(v)); }
__device__ __forceinline__ u64 ald(const u64* p){
    return __hip_atomic_load((u64*)p, __ATOMIC_RELAXED, __HIP_MEMORY_SCOPE_AGENT);
}
__device__ __forceinline__ void ast(u64* p, u64 v){
    __hip_atomic_store(p, v, __ATOMIC_RELAXED, __HIP_MEMORY_SCOPE_AGENT);
}
__device__ __forceinline__ u32 pkh(float a, float b){   // fp32x2 -> packed f16 RNE
    f16x2 v = { (f16)a, (f16)b };
    return __builtin_bit_cast(u32, v);
}
__device__ __forceinline__ float unpk(u32 u, int hi){
    f16x2 v = __builtin_bit_cast(f16x2, u);
    return (float)v[hi];
}
__device__ __forceinline__ float dot2(u32 a, u32 b, float c){
#if __has_builtin(__builtin_amdgcn_fdot2)
    return __builtin_amdgcn_fdot2(__builtin_bit_cast(f16x2, a),
                                  __builtin_bit_cast(f16x2, b), c, false);
#else
    f16x2 av = __builtin_bit_cast(f16x2, a), bv = __builtin_bit_cast(f16x2, b);
    return c + (float)av[0]*(float)bv[0] + (float)av[1]*(float)bv[1];
#endif
}
__device__ __forceinline__ u32 poll1u(const u64* p, u32 tag){
    u64 v; do { v = ald(p); } while ((u32)(v >> 32) != tag);
    return (u32)v;
}
// 64 lanes fetch 100 tagged slots (lane l gets l and l+64 if <100)
__device__ __forceinline__ void poll100(const u64* base, u32 tag, int l,
                                        u32* o0, u32* o1){
    const bool g1 = (l + 64 < 100);
    u64 v0, v1 = 0;
    for(;;){
        v0 = ald(base + l);
        if (g1) v1 = ald(base + l + 64);
        if ((u32)(v0>>32)==tag && (!g1 || (u32)(v1>>32)==tag)) break;
    }
    *o0 = (u32)v0;
    *o1 = (u32)v1;
}

// Grid of 16 (bid%8 -> XCD): pairs (0,8)=L0 halves, (1,9)=L1 halves,
// (2,10,3,11)=pre1 gates 0..3. 512 threads (128-VGPR budget, r9-proven).
// Recurrence F-phase = MFMA 16x16x32_f16: weights live as per-wave A-frags
// (84 uint4/lane, 3 row-tiles x 7 K-tiles, K padded to 224), h is the
// B-operand read as 7 small grouped LDS loads/wave -- replaces r9's
// 28 ds_read_b128 broadcasts/wave (the ~1000cy/step LDS-pipe tax).
// Rows 384..399 via a 7-pair dot2 strip on waves 0-3. 16 remainder rows.
__global__ __launch_bounds__(512)
__attribute__((amdgpu_waves_per_eu(2, 4)))
void lstm_pipe(const float* __restrict__ x,
               const float* __restrict__ Wih0, const float* __restrict__ Whh0,
               const float* __restrict__ bih0, const float* __restrict__ bhh0,
               const float* __restrict__ Wih1, const float* __restrict__ Whh1,
               const float* __restrict__ bih1, const float* __restrict__ bhh1,
               const float* __restrict__ Wout, const float* __restrict__ bout,
               u64* __restrict__ hp0,   // [TT][100] tagged packed-f16 h0 pairs
               u64* __restrict__ p1r,   // [RD][800] tagged fp32 ring
               u64* __restrict__ h1x,   // [64][100] tagged packed-f16 h1 pairs
               u32* __restrict__ prog,  // [1] layer-1 progress
               float* __restrict__ out)
{
    const int bid = blockIdx.x;
    const int tid = threadIdx.x;

    __shared__ float xs[TT];                        // 32,768B (L0 only)
    __shared__ __align__(16) u32 hp_lds[2][112];    // packed h f16[224], zero-pad
    __shared__ u32 hpbuf[2][100];                   // pre1 h0 dbuf
    __shared__ float s_pre[400];
    __shared__ float s_in[2][400];                  // L1 staged pre1 (dbuf)
    __shared__ float wihL[400], bsL[400];           // L0 per-row x-weight/bias
    __shared__ float h32[100];

    // role decode
    int role = -1, L = 0, hf = 0, q = 0;
    if      (bid == 0)  { role = 0; L = 0; hf = 0; }
    else if (bid == 8)  { role = 0; L = 0; hf = 1; }
    else if (bid == 1)  { role = 0; L = 1; hf = 0; }
    else if (bid == 9)  { role = 0; L = 1; hf = 1; }
    else if (bid == 2)  { role = 1; q = 0; }
    else if (bid == 10) { role = 1; q = 1; }
    else if (bid == 3)  { role = 1; q = 2; }
    else if (bid == 11) { role = 1; q = 3; }
    if (role < 0) return;

    // ================= pre1 streaming stage (r9 verbatim) =================
    if (role == 1) {
        const int rl = tid >> 1, kh = tid & 1;
        const bool act = (tid < 400);
        u32 wp[50]; float bs = 0.f; int row = 0;
        if (act) {
            row = q * 200 + rl;
            const float* wr = Wih1 + (size_t)row * HH + kh * 100;
            #pragma unroll
            for (int i = 0; i < 50; ++i) wp[i] = pkh(wr[2*i], wr[2*i+1]);
            #pragma unroll
            for (int i = 0; i < 50; ++i) asm volatile("" : "+v"(wp[i]));
            if (kh == 0) bs = bih1[row] + bhh1[row];
        } else if (tid >= 448) {
            u32 o0, o1;
            poll100(hp0, 1u, tid - 448, &o0, &o1);
            hpbuf[0][tid - 448] = o0;
            if (tid - 448 + 64 < 100) hpbuf[0][tid - 448 + 64] = o1;
        }
        u32 prog_c = 0;
        __syncthreads();
        for (int t = 0; t < TT; ++t) {
            if (act) {
                const u32* hb = hpbuf[t & 1] + kh * 50;
                float a0 = 0.f, a1 = 0.f;
                #pragma unroll
                for (int i = 0; i < 50; i += 2) a0 = dot2(wp[i], hb[i], a0);
                #pragma unroll
                for (int i = 1; i < 50; i += 2) a1 = dot2(wp[i], hb[i], a1);
                float s = a0 + a1;
                s += __shfl_xor(s, 1);
                if (kh == 0)
                    ast(&p1r[(size_t)(t & RDM) * 800 + q * 200 + rl],
                        pckf((u32)(t + 1), s + bs));
            } else if (tid >= 448) {
                if (t + 1 < TT) {
                    u32 o0, o1;
                    poll100(&hp0[(size_t)(t + 1) * 100], (u32)(t + 2),
                            tid - 448, &o0, &o1);
                    hpbuf[(t + 1) & 1][tid - 448] = o0;
                    if (tid - 448 + 64 < 100) hpbuf[(t + 1) & 1][tid - 448 + 64] = o1;
                }
            } else if (tid == 440) {
                while ((int)(t + 1) - (int)prog_c >= BPWIN) {
                    __builtin_amdgcn_s_sleep(8);
                    prog_c = __hip_atomic_load(prog, __ATOMIC_RELAXED,
                                               __HIP_MEMORY_SCOPE_AGENT);
                }
            }
            __syncthreads();
        }
        return;
    }

    // ================= recurrence half-blocks =================
    const int nb = hf * 100;                 // own neuron base
    const int pb = (1 - hf) * 100;           // partner neuron base
    const float* Whh = L ? Whh1 : Whh0;

    const int wv = tid >> 6, ln = tid & 63;
    const int lrow16 = ln & 15, lkgrp = ln >> 4;

    // ---- A-fragments: 3 row-tiles x 7 K-tiles, pinned in VGPRs ----
    // layout bet: A[16x32] lane l holds row=l&15, k = 8*(l>>4)+e (e=0..7)
    uint4 au[3][7];
    #pragma unroll
    for (int tt2 = 0; tt2 < 3; ++tt2) {
        const int rl = 16 * (wv * 3 + tt2) + lrow16;       // local row 0..383
        const int g  = (rl / 100) * 200 + nb + (rl % 100); // global gate row
        const float* wr = Whh + (size_t)g * HH;
        #pragma unroll
        for (int kt = 0; kt < 7; ++kt) {
            const int kb = kt * 32 + lkgrp * 8;
            float w8[8];
            #pragma unroll
            for (int e = 0; e < 8; ++e) w8[e] = (kb + e < HH) ? wr[kb + e] : 0.f;
            au[tt2][kt] = make_uint4(pkh(w8[0],w8[1]), pkh(w8[2],w8[3]),
                                     pkh(w8[4],w8[5]), pkh(w8[6],w8[7]));
            asm volatile("" : "+v"(au[tt2][kt].x), "+v"(au[tt2][kt].y),
                              "+v"(au[tt2][kt].z), "+v"(au[tt2][kt].w));
        }
    }
    // ---- remainder rows 384..399: dot2 strip on waves 0-3 ----
    u32 wr7[7]; int remrow = 0;
    if (wv < 4) {
        remrow = 384 + wv * 4 + lkgrp;
        const int g = (remrow / 100) * 200 + nb + (remrow % 100);
        const float* wr = Whh + (size_t)g * HH;
        #pragma unroll
        for (int j = 0; j < 7; ++j) {
            const int k = 14 * lrow16 + 2 * j;
            wr7[j] = pkh(k < HH ? wr[k] : 0.f, k + 1 < HH ? wr[k+1] : 0.f);
            asm volatile("" : "+v"(wr7[j]));
        }
    }
    if (L == 0) {
        for (int i = tid; i < TT; i += 512) xs[i] = x[i];
        if (tid < 400) {
            const int g = (tid / 100) * 200 + nb + (tid % 100);
            wihL[tid] = Wih0[g];
            bsL[tid]  = bih0[g] + bhh0[g];
        }
    }
    if (tid < 112) { hp_lds[0][tid] = 0u; hp_lds[1][tid] = 0u; }
    if (tid < 100) h32[tid] = 0.f;

    // L1: preload pre1[0] into s_in[0] (wave 6)
    if (L == 1 && wv == 6) {
        u64 v[7];
        for(;;){
            #pragma unroll
            for (int r2 = 0; r2 < 7; ++r2) {
                const int m = ln + 64 * r2;
                if (m < 400) v[r2] = ald(&p1r[(m/100)*200 + nb + (m%100)]);
            }
            bool ok = true;
            #pragma unroll
            for (int r2 = 0; r2 < 7; ++r2) {
                const int m = ln + 64 * r2;
                if (m < 400 && (u32)(v[r2]>>32) != 1u) ok = false;
            }
            if (ok) break;
        }
        #pragma unroll
        for (int r2 = 0; r2 < 7; ++r2) {
            const int m = ln + 64 * r2;
            if (m < 400) s_in[0][m] = __uint_as_float((u32)v[r2]);
        }
    }
    float c = 0.f;
    __syncthreads();

    for (int t = 0; t < TT; ++t) {
        const int p = t & 1;
        // ---------- phase F: MFMA matvec ----------
        {
            f32x4 d0 = {0.f,0.f,0.f,0.f}, d1 = {0.f,0.f,0.f,0.f},
                  d2 = {0.f,0.f,0.f,0.f};
            const uint4* hp4 = (const uint4*)hp_lds[p];
            #pragma unroll
            for (int kt = 0; kt < 7; ++kt) {
                const half8 b = __builtin_bit_cast(half8, hp4[kt * 4 + lkgrp]);
                d0 = __builtin_amdgcn_mfma_f32_16x16x32_f16(
                         __builtin_bit_cast(half8, au[0][kt]), b, d0, 0, 0, 0);
                d1 = __builtin_amdgcn_mfma_f32_16x16x32_f16(
                         __builtin_bit_cast(half8, au[1][kt]), b, d1, 0, 0, 0);
                d2 = __builtin_amdgcn_mfma_f32_16x16x32_f16(
                         __builtin_bit_cast(half8, au[2][kt]), b, d2, 0, 0, 0);
            }
            // D layout (m89-verified): col=lane&15, row=4*(lane>>4)+r
            if (lrow16 == 0) {
                const int rb = lkgrp * 4;
                #pragma unroll
                for (int r2 = 0; r2 < 4; ++r2) {
                    s_pre[16*(wv*3+0) + rb + r2] = d0[r2];
                    s_pre[16*(wv*3+1) + rb + r2] = d1[r2];
                    s_pre[16*(wv*3+2) + rb + r2] = d2[r2];
                }
            }
            if (wv < 4) {   // remainder rows
                float s = 0.f;
                #pragma unroll
                for (int j = 0; j < 7; ++j)
                    s = dot2(wr7[j], hp_lds[p][7*lrow16 + j], s);
                s += __shfl_xor(s, 1); s += __shfl_xor(s, 2);
                s += __shfl_xor(s, 4); s += __shfl_xor(s, 8);
                if (lrow16 == 0) s_pre[remrow] = s;
            }
        }
        __syncthreads();
        // ---------- phase G: gates || partner poll || L1 ring restage ----------
        if (tid < 100) {
            const int n = tid;
            float g0 = s_pre[n],       g1 = s_pre[100 + n],
                  g2 = s_pre[200 + n], g3 = s_pre[300 + n];
            if (L == 0) {
                const float xv = xs[t];
                g0 += xv * wihL[n]       + bsL[n];
                g1 += xv * wihL[100 + n] + bsL[100 + n];
                g2 += xv * wihL[200 + n] + bsL[200 + n];
                g3 += xv * wihL[300 + n] + bsL[300 + n];
            } else {
                g0 += s_in[p][n];       g1 += s_in[p][100 + n];
                g2 += s_in[p][200 + n]; g3 += s_in[p][300 + n];
            }
            const float ig = sigmoidf_(g0), fg = sigmoidf_(g1);
            const float gg = tanhf_(g2),    og = sigmoidf_(g3);
            c = fg * c + ig * gg;
            const float h = og * tanhf_(c);
            h32[n] = h;
            const float hq = __shfl_xor(h, 1);
            if (!(n & 1)) {
                const u32 pk = pkh(h, hq);
                hp_lds[p ^ 1][(nb >> 1) + (n >> 1)] = pk;
                if (L == 0)
                    ast(&hp0[(size_t)t * 100 + (nb >> 1) + (n >> 1)],
                        pcku((u32)(t + 1), pk));
                else
                    ast(&h1x[(size_t)(t & 63) * 100 + (nb >> 1) + (n >> 1)],
                        pcku((u32)(t + 1), pk));
            }
        } else if (wv == 7) {
            if (ln < 50) {
                const u64* src = (L == 0)
                    ? &hp0[(size_t)t * 100 + (pb >> 1) + ln]
                    : &h1x[(size_t)(t & 63) * 100 + (pb >> 1) + ln];
                hp_lds[p ^ 1][(pb >> 1) + ln] = poll1u(src, (u32)(t + 1));
            }
        } else if (L == 1 && wv == 6) {
            if (t + 1 < TT) {   // ring runs ~1000 ahead -> immediate hit
                const u64* slot = &p1r[(size_t)((t + 1) & RDM) * 800];
                const u32 tg = (u32)(t + 2);
                u64 v[7];
                for(;;){
                    #pragma unroll
                    for (int r2 = 0; r2 < 7; ++r2) {
                        const int m = ln + 64 * r2;
                        if (m < 400) v[r2] = ald(slot + (m/100)*200 + nb + (m%100));
                    }
                    bool ok = true;
                    #pragma unroll
                    for (int r2 = 0; r2 < 7; ++r2) {
                        const int m = ln + 64 * r2;
                        if (m < 400 && (u32)(v[r2]>>32) != tg) ok = false;
                    }
                    if (ok) break;
                }
                #pragma unroll
                for (int r2 = 0; r2 < 7; ++r2) {
                    const int m = ln + 64 * r2;
                    if (m < 400) s_in[p ^ 1][m] = __uint_as_float((u32)v[r2]);
                }
            }
        } else if (L == 1 && hf == 0 && tid == 100 && (t & 63) == 63) {
            __hip_atomic_store(prog, (u32)(t + 1), __ATOMIC_RELAXED,
                               __HIP_MEMORY_SCOPE_AGENT);
        }
        __syncthreads();
    }

    // ---- linear head on final h1 (L1 half 0) ----
    if (L == 1 && hf == 0 && tid < 64) {
        const int fin = ((TT - 1) & 1) ^ 1;
        float s2 = 0.f;
        for (int k = tid; k < HH; k += 64) {
            float hv;
            if (k < 100) hv = h32[k];
            else         hv = unpk(hp_lds[fin][50 + ((k - 100) >> 1)], (k - 100) & 1);
            s2 += hv * Wout[k];
        }
        #pragma unroll
        for (int off = 32; off > 0; off >>= 1) s2 += __shfl_down(s2, off);
        if (tid == 0) out[0] = s2 + bout[0];
    }
}

extern "C" void kernel_launch(void* const* d_in, const int* in_sizes, int n_in,
                              void* d_out, int out_size, void* d_ws, size_t ws_size,
                              hipStream_t stream) {
    const float* x    = (const float*)d_in[0];
    const float* Wih0 = (const float*)d_in[1];
    const float* Whh0 = (const float*)d_in[2];
    const float* bih0 = (const float*)d_in[3];
    const float* bhh0 = (const float*)d_in[4];
    const float* Wih1 = (const float*)d_in[5];
    const float* Whh1 = (const float*)d_in[6];
    const float* bih1 = (const float*)d_in[7];
    const float* bhh1 = (const float*)d_in[8];
    const float* Wout = (const float*)d_in[9];
    const float* bout = (const float*)d_in[10];
    float* out = (float*)d_out;

    char* ws = (char*)d_ws;
    // hp0 6,553,600 | p1r 6,553,600 | h1x 51,200 | prog 64
    u64* hp0  = (u64*)ws;
    u64* p1r  = (u64*)(ws + 6553600);
    u64* h1x  = (u64*)(ws + 13107200);
    u32* prog = (u32*)(ws + 13158400);

    // clear all tags/progress every launch (graph-safe, deterministic)
    hipMemsetAsync(ws, 0, 13158464, stream);

    hipLaunchKernelGGL(lstm_pipe, dim3(16), dim3(512), 0, stream,
        x, Wih0, Whh0, bih0, bhh0, Wih1, Whh1, bih1, bhh1, Wout, bout,
        hp0, p1r, h1x, prog, out);
}